// Round 1
// baseline (3102.635 us; speedup 1.0000x reference)
//
#include <hip/hip_runtime.h>

// LSTM: B=256, T=8192, I=5, H=16, fc -> 1.
// One wave (64 lanes) per batch element. Lane g owns gate g (q = g>>4:
// 0=i, 1=f, 2=g(tanh), 3=o; j = g&15 = hidden index).
// Sequential over T; per-step critical chain minimized:
//   readlane h -> 4x4 FMA chains -> exp-activation -> bpermute gather ->
//   c fma -> tanh(c) -> h mul.

__device__ __forceinline__ float readlane_f(float v, int l) {
    return __int_as_float(__builtin_amdgcn_readlane(__float_as_int(v), l));
}

__device__ __forceinline__ float fast_rcp(float v) {
    return __builtin_amdgcn_rcpf(v);
}

__global__ __launch_bounds__(64, 1) void lstm_fused(
    const float* __restrict__ x,      // [B, T, 5]
    const float* __restrict__ W_ih,   // [64, 5]
    const float* __restrict__ W_hh,   // [64, 16]
    const float* __restrict__ b_ih,   // [64]
    const float* __restrict__ b_hh,   // [64]
    const float* __restrict__ fc_w,   // [1, 16]
    const float* __restrict__ fc_b,   // [1]
    float* __restrict__ out,          // [B, T]
    int T)
{
    const int b    = blockIdx.x;
    const int lane = threadIdx.x;     // 0..63
    const int j    = lane & 15;
    const int q    = lane >> 4;

    // Per-lane weights (held in VGPRs for the whole sequence).
    const float wi0 = W_ih[lane * 5 + 0];
    const float wi1 = W_ih[lane * 5 + 1];
    const float wi2 = W_ih[lane * 5 + 2];
    const float wi3 = W_ih[lane * 5 + 3];
    const float wi4 = W_ih[lane * 5 + 4];
    float wh[16];
#pragma unroll
    for (int k = 0; k < 16; ++k) wh[k] = W_hh[lane * 16 + k];
    const float bias = b_ih[lane] + b_hh[lane];
    const float fcw  = fc_w[j];
    const float fcb  = fc_b[0];

    // Activation selectors: tanh(x) = 2*sigmoid(2x) - 1.
    const bool  isg    = (q == 2);
    const float pre_s  = isg ? -2.0f : -1.0f;  // exp(pre_s * pre)
    const float post_m = isg ?  2.0f :  1.0f;
    const float post_a = isg ? -1.0f :  0.0f;

    const float* __restrict__ xb = x   + (size_t)b * T * 5;
    float*       __restrict__ yb = out + (size_t)b * T;

    float c = 0.0f;
    float h = 0.0f;    // h[j], replicated identically in all 4 lane-groups
    float yv = 0.0f;   // per-lane output staging (coalesced store each 64 steps)

    // Prefetch x for t=0.
    float xa0 = xb[0], xa1 = xb[1], xa2 = xb[2], xa3 = xb[3], xa4 = xb[4];

    for (int t = 0; t < T; ++t) {
        // Prefetch next step's x (wave-uniform address -> scalar loads).
        const int tn = (t + 1 < T) ? (t + 1) : t;
        const float* __restrict__ xn = xb + (size_t)tn * 5;
        const float nx0 = xn[0], nx1 = xn[1], nx2 = xn[2], nx3 = xn[3], nx4 = xn[4];

        // Gate preactivation: bias + x.W_ih + h.W_hh, 4 parallel FMA chains.
        float a0 = fmaf(xa0, wi0, bias);
        a0 = fmaf(xa4, wi4, a0);
        float a1 = xa1 * wi1;
        float a2 = xa2 * wi2;
        float a3 = xa3 * wi3;
#pragma unroll
        for (int k = 0; k < 4; ++k) a0 = fmaf(readlane_f(h, k),      wh[k],      a0);
#pragma unroll
        for (int k = 0; k < 4; ++k) a1 = fmaf(readlane_f(h, k + 4),  wh[k + 4],  a1);
#pragma unroll
        for (int k = 0; k < 4; ++k) a2 = fmaf(readlane_f(h, k + 8),  wh[k + 8],  a2);
#pragma unroll
        for (int k = 0; k < 4; ++k) a3 = fmaf(readlane_f(h, k + 12), wh[k + 12], a3);
        const float pre = (a0 + a1) + (a2 + a3);

        // Activation (sigmoid, or tanh via 2*sigmoid(2x)-1). No divergence.
        const float e   = __expf(pre_s * pre);
        const float s   = fast_rcp(1.0f + e);
        const float act = fmaf(post_m, s, post_a);

        // Gather i, f, g, o for hidden index j (all lanes, redundant by group).
        const float iv = __shfl(act, j,      64);
        const float fv = __shfl(act, j + 16, 64);
        const float gv = __shfl(act, j + 32, 64);
        const float ov = __shfl(act, j + 48, 64);

        // State update.
        c = fmaf(fv, c, iv * gv);
        const float e2 = __expf(-2.0f * c);
        const float r  = fast_rcp(1.0f + e2);
        const float th = fmaf(2.0f, r, -1.0f);
        h = ov * th;

        // Output projection y = h . fc_w + fc_b (off the recurrence chain).
        float p = h * fcw;
        p += __shfl_xor(p, 1, 64);
        p += __shfl_xor(p, 2, 64);
        p += __shfl_xor(p, 4, 64);
        p += __shfl_xor(p, 8, 64);
        const float yu = readlane_f(p, 0) + fcb;

        // Stage into lane (t&63); store 64 coalesced values every 64 steps.
        yv = (lane == (t & 63)) ? yu : yv;
        if ((t & 63) == 63) {
            yb[(t & ~63) + lane] = yv;
        }

        xa0 = nx0; xa1 = nx1; xa2 = nx2; xa3 = nx3; xa4 = nx4;
    }
}

extern "C" void kernel_launch(void* const* d_in, const int* in_sizes, int n_in,
                              void* d_out, int out_size, void* d_ws, size_t ws_size,
                              hipStream_t stream) {
    const float* x    = (const float*)d_in[0];
    const float* W_ih = (const float*)d_in[1];
    const float* W_hh = (const float*)d_in[2];
    const float* b_ih = (const float*)d_in[3];
    const float* b_hh = (const float*)d_in[4];
    const float* fc_w = (const float*)d_in[5];
    const float* fc_b = (const float*)d_in[6];
    float* out = (float*)d_out;

    const int B = 256;                 // fixed by the problem
    const int T = out_size / B;        // 8192 (multiple of 64)

    lstm_fused<<<dim3(B), dim3(64), 0, stream>>>(
        x, W_ih, W_hh, b_ih, b_hh, fc_w, fc_b, out, T);
}

// Round 3
// 1224.707 us; speedup vs baseline: 2.5334x; 2.5334x over previous
//
#include <hip/hip_runtime.h>

// LSTM: B=256, T=8192, I=5, H=16, fc -> 1.  One wave per batch element.
// Lane g owns gate g (q = g>>4: 0=i,1=f,2=g(tanh),3=o; j = g&15).
// Per-step chain: readlane h -> 4x4 FMA chains -> exp2 -> permlane gather ->
// c fma -> tanh(c) -> h.  Output projection batched every 64 steps via LDS.
// x staged through double-buffered LDS, one 64-step chunk ahead.
//
// R2 failed: inline-asm permlane*_swap with two "+v" operands holding the
// SAME value let the register allocator coalesce them into one VGPR ->
// v_permlane32_swap_b32 v0,v0 -> gates crossed (absmax 0.22). Fix: use the
// pair-returning builtins, which keep vdst/vsrc distinct by construction.

// If the swap pair order is mirrored on HW, set to 1 (doc says 0 is right).
#define SWAP_MIRROR 0

__device__ __forceinline__ float readlane_f(float v, int l) {
    return __int_as_float(__builtin_amdgcn_readlane(__float_as_int(v), l));
}

__device__ __forceinline__ void plswap32(float& a, float& b) {
#if __has_builtin(__builtin_amdgcn_permlane32_swap)
    auto r = __builtin_amdgcn_permlane32_swap(__float_as_uint(a),
                                              __float_as_uint(b), false, false);
    a = __uint_as_float(r[0]);
    b = __uint_as_float(r[1]);
#else
    unsigned ao, bo;
    asm("v_mov_b32 %0, %2\n\t"
        "v_mov_b32 %1, %3\n\t"
        "v_permlane32_swap_b32 %0, %1"
        : "=&v"(ao), "=&v"(bo)
        : "v"(__float_as_uint(a)), "v"(__float_as_uint(b)));
    a = __uint_as_float(ao);
    b = __uint_as_float(bo);
#endif
}

__device__ __forceinline__ void plswap16(float& a, float& b) {
#if __has_builtin(__builtin_amdgcn_permlane16_swap)
    auto r = __builtin_amdgcn_permlane16_swap(__float_as_uint(a),
                                              __float_as_uint(b), false, false);
    a = __uint_as_float(r[0]);
    b = __uint_as_float(r[1]);
#else
    unsigned ao, bo;
    asm("v_mov_b32 %0, %2\n\t"
        "v_mov_b32 %1, %3\n\t"
        "v_permlane16_swap_b32 %0, %1"
        : "=&v"(ao), "=&v"(bo)
        : "v"(__float_as_uint(a)), "v"(__float_as_uint(b)));
    a = __uint_as_float(ao);
    b = __uint_as_float(bo);
#endif
}

__global__ __launch_bounds__(64, 1) void lstm_fused(
    const float* __restrict__ x,      // [B, T, 5]
    const float* __restrict__ W_ih,   // [64, 5]
    const float* __restrict__ W_hh,   // [64, 16]
    const float* __restrict__ b_ih,   // [64]
    const float* __restrict__ b_hh,   // [64]
    const float* __restrict__ fc_w,   // [1, 16]
    const float* __restrict__ fc_b,   // [1]
    float* __restrict__ out,          // [B, T]
    int T)
{
    const int b    = blockIdx.x;
    const int lane = threadIdx.x;     // 0..63
    const int j    = lane & 15;
    const int q    = lane >> 4;
    const bool isg = (q == 2);

    // Pre-scale weights by -log2(e) (sigmoid) or -2*log2(e) (tanh gate) so the
    // activation is exp2(pre) directly: sigma(z) = 1/(1+2^(-z*log2e)).
    const float LOG2E  = 1.4426950408889634f;
    const float wscale = isg ? (-2.0f * LOG2E) : (-LOG2E);
    const float post_m = isg ?  2.0f : 1.0f;
    const float post_a = isg ? -1.0f : 0.0f;

    float wi[5];
#pragma unroll
    for (int i = 0; i < 5; ++i)  wi[i] = W_ih[lane * 5 + i] * wscale;
    float wh[16];
#pragma unroll
    for (int k = 0; k < 16; ++k) wh[k] = W_hh[lane * 16 + k] * wscale;
    const float bias = (b_ih[lane] + b_hh[lane]) * wscale;

    float fw[16];                      // uniform -> SGPRs
#pragma unroll
    for (int k = 0; k < 16; ++k) fw[k] = fc_w[k];
    const float fcb = fc_b[0];

    __shared__ float ls_x[640];        // 2 buffers x 64 steps x 5
    __shared__ float ls_h[64 * 17];    // stride 17 to avoid bank conflicts

    const float* __restrict__ xb = x   + (size_t)b * T * 5;
    float*       __restrict__ yb = out + (size_t)b * T;
    const int NC = T >> 6;             // 64-step chunks

    // ---- Prologue: chunk 0 -> LDS buf0; chunk 1 loads in flight in rp. ----
    float r0[5], rp[5];
#pragma unroll
    for (int k = 0; k < 5; ++k) r0[k] = xb[64 * k + lane];
#pragma unroll
    for (int k = 0; k < 5; ++k) rp[k] = (NC > 1) ? xb[320 + 64 * k + lane] : 0.0f;
#pragma unroll
    for (int k = 0; k < 5; ++k) ls_x[64 * k + lane] = r0[k];

    // Preload x rows 0 and 1 (uniform-address broadcast reads).
    float xa[5], xn[5];
#pragma unroll
    for (int i = 0; i < 5; ++i) xa[i] = ls_x[i];
#pragma unroll
    for (int i = 0; i < 5; ++i) xn[i] = ls_x[5 + i];

    float c = 0.0f, h = 0.0f;

    for (int n = 0; n < NC; ++n) {
        const int bofs = (n & 1) * 320;

        // Stage chunk n+1 into the other buffer; issue loads for chunk n+2.
        if (n + 1 < NC) {
            const int dst = ((n + 1) & 1) * 320;
#pragma unroll
            for (int k = 0; k < 5; ++k) ls_x[dst + 64 * k + lane] = rp[k];
            if (n + 2 < NC) {
#pragma unroll
                for (int k = 0; k < 5; ++k)
                    rp[k] = xb[(size_t)(n + 2) * 320 + 64 * k + lane];
            }
        }

#pragma unroll 2
        for (int tp = 0; tp < 64; ++tp) {
            // Prefetch x row tp+2 (wraps into the other buffer at 62/63; for
            // the last chunk those values are loaded-but-never-consumed).
            int w = bofs + 5 * (tp + 2);
            w = (w >= 640) ? (w - 640) : w;
            const float p0 = ls_x[w],     p1 = ls_x[w + 1], p2 = ls_x[w + 2];
            const float p3 = ls_x[w + 3], p4 = ls_x[w + 4];

            // Gate preactivation (already scaled by -log2e / -2log2e).
            float a0 = fmaf(xa[0], wi[0], bias);
            a0 = fmaf(xa[4], wi[4], a0);
            float a1 = xa[1] * wi[1];
            float a2 = xa[2] * wi[2];
            float a3 = xa[3] * wi[3];
#pragma unroll
            for (int k = 0; k < 4; ++k) a0 = fmaf(readlane_f(h, k),      wh[k],      a0);
#pragma unroll
            for (int k = 0; k < 4; ++k) a1 = fmaf(readlane_f(h, k + 4),  wh[k + 4],  a1);
#pragma unroll
            for (int k = 0; k < 4; ++k) a2 = fmaf(readlane_f(h, k + 8),  wh[k + 8],  a2);
#pragma unroll
            for (int k = 0; k < 4; ++k) a3 = fmaf(readlane_f(h, k + 12), wh[k + 12], a3);
            const float pre = (a0 + a1) + (a2 + a3);

            // Activation: sigma or tanh (=2*sigma(2z)-1), via exp2 + rcp.
            const float e   = __builtin_amdgcn_exp2f(pre);
            const float s   = __builtin_amdgcn_rcpf(1.0f + e);
            const float act = fmaf(post_m, s, post_a);

            // Gather i,f,g,o to all lanes: VALU-speed permlane swaps.
            float A1 = act, B1 = act;
            plswap32(A1, B1);          // A1=[i,f,i,f] rows, B1=[g,o,g,o]
            float iv = A1, fv = A1;
            plswap16(iv, fv);          // iv=[i x4], fv=[f x4]
            float gv = B1, ov = B1;
            plswap16(gv, ov);          // gv=[g x4], ov=[o x4]
#if SWAP_MIRROR
            { float t = iv; iv = fv; fv = t; }
            { float t = gv; gv = ov; ov = t; }
#endif

            // State update.
            c = fmaf(fv, c, iv * gv);
            const float e2 = __builtin_amdgcn_exp2f(c * -2.8853900817779268f); // -2*log2e
            const float r2 = __builtin_amdgcn_rcpf(1.0f + e2);
            h = ov * fmaf(2.0f, r2, -1.0f);

            // Stage h for the batched output projection (no wait needed).
            ls_h[tp * 17 + j] = h;

            // Rotate x registers.
#pragma unroll
            for (int i = 0; i < 5; ++i) { xa[i] = xn[i]; }
            xn[0] = p0; xn[1] = p1; xn[2] = p2; xn[3] = p3; xn[4] = p4;
        }

        // ---- Batched output projection: lane l handles step n*64+l. ----
        float hrow[16];
#pragma unroll
        for (int k = 0; k < 16; ++k) hrow[k] = ls_h[lane * 17 + k];
        float y = fcb;
#pragma unroll
        for (int k = 0; k < 16; ++k) y = fmaf(hrow[k], fw[k], y);
        yb[(n << 6) + lane] = y;
    }
}

extern "C" void kernel_launch(void* const* d_in, const int* in_sizes, int n_in,
                              void* d_out, int out_size, void* d_ws, size_t ws_size,
                              hipStream_t stream) {
    const float* x    = (const float*)d_in[0];
    const float* W_ih = (const float*)d_in[1];
    const float* W_hh = (const float*)d_in[2];
    const float* b_ih = (const float*)d_in[3];
    const float* b_hh = (const float*)d_in[4];
    const float* fc_w = (const float*)d_in[5];
    const float* fc_b = (const float*)d_in[6];
    float* out = (float*)d_out;

    const int B = 256;
    const int T = out_size / B;   // 8192

    lstm_fused<<<dim3(B), dim3(64), 0, stream>>>(
        x, W_ih, W_hh, b_ih, b_hh, fc_w, fc_b, out, T);
}